// Round 5
// baseline (43.059 us; speedup 1.0000x reference)
//
#include <hip/hip_runtime.h>

// P1 (CG1) function evaluation, two-pass affine-collapse, v5.
//
// out[p] = alpha[c] + beta[c]*px + gamma[c]*py,  c = cell_ids[p].
//
// Rounds 2/3/4: 12B/16B/8B table records all ~42-49 us -> time is per gather
// REQUEST, not per byte (L1 line-fill / MSHR bound: random 8B gathers all miss
// the 32KB L1; ~64 fills in flight vs ~200cy L2 latency caps ~0.3 lines/cy/CU).
// v5 single-variable change: table gathers use agent-scope relaxed loads
// (L1 bypass, sc0) so they don't allocate/track L1 fills; L2 serves directly.

typedef float    f4 __attribute__((ext_vector_type(4)));
typedef float    f2 __attribute__((ext_vector_type(2)));
typedef int      i4 __attribute__((ext_vector_type(4)));
typedef unsigned u2 __attribute__((ext_vector_type(2)));

__device__ __forceinline__ unsigned bf16_rne_hi(float f) {
    unsigned u = __float_as_uint(f);
    return (u + 0x7fffu + ((u >> 16) & 1u)) >> 16;   // round-to-nearest-even
}

__global__ __launch_bounds__(256) void p1_precompute_kernel(
    const float* __restrict__ Minv,    // (N_CELLS, 2, 2)
    const float* __restrict__ A,       // (N_CELLS, 2)
    const float* __restrict__ weight,  // (N_DOFS,)
    const int*   __restrict__ dofs,    // (N_CELLS, 3)
    unsigned long long* __restrict__ table, // (N_CELLS) 8 B: {f32 alpha | bf16 beta,gamma}
    int n_cells)
{
    int c = blockIdx.x * blockDim.x + threadIdx.x;
    if (c >= n_cells) return;

    f4 M = ((const f4*)Minv)[c];       // m00, m01, m10, m11
    f2 a = ((const f2*)A)[c];
    int d0 = dofs[3 * c + 0];
    int d1 = dofs[3 * c + 1];
    int d2 = dofs[3 * c + 2];
    float c0 = weight[d0];
    float c1 = weight[d1];
    float c2 = weight[d2];

    float w1 = c1 - c0, w2 = c2 - c0;
    float beta  = M.x * w1 + M.y * w2;
    float gamma = M.z * w1 + M.w * w2;
    float alpha = c0 - a.x * beta - a.y * gamma;

    unsigned hi = (bf16_rne_hi(beta) << 16) | bf16_rne_hi(gamma);
    unsigned long long rec =
        (unsigned long long)__float_as_uint(alpha) | ((unsigned long long)hi << 32);
    table[c] = rec;
}

__device__ __forceinline__ float eval_rec(unsigned long long rec, float px, float py) {
    float al = __uint_as_float((unsigned)rec);
    unsigned hi = (unsigned)(rec >> 32);
    float be = __uint_as_float(hi & 0xffff0000u);
    float ga = __uint_as_float(hi << 16);
    return fmaf(py, ga, fmaf(px, be, al));
}

__global__ __launch_bounds__(256) void p1_eval_fast(
    const float* __restrict__ x,         // (N_PTS, 2)
    const int*   __restrict__ cell_ids,  // (N_PTS,)
    const unsigned long long* __restrict__ table, // (N_CELLS) 8 B records
    float*       __restrict__ out,       // (N_PTS,)
    int n_quads)                          // N_PTS / 4
{
    int i = blockIdx.x * blockDim.x + threadIdx.x;
    if (i >= n_quads) return;

    // Streaming (non-temporal): 4 points per thread.
    i4 c4  = __builtin_nontemporal_load((const i4*)cell_ids + i);

    // Agent-scope relaxed loads = L1-bypass (sc0) gathers from the
    // L2-resident 2 MB table: no L1 fill allocation / MSHR pressure.
    unsigned long long t0 = __hip_atomic_load(table + c4.x, __ATOMIC_RELAXED, __HIP_MEMORY_SCOPE_AGENT);
    unsigned long long t1 = __hip_atomic_load(table + c4.y, __ATOMIC_RELAXED, __HIP_MEMORY_SCOPE_AGENT);
    unsigned long long t2 = __hip_atomic_load(table + c4.z, __ATOMIC_RELAXED, __HIP_MEMORY_SCOPE_AGENT);
    unsigned long long t3 = __hip_atomic_load(table + c4.w, __ATOMIC_RELAXED, __HIP_MEMORY_SCOPE_AGENT);

    f4 p01 = __builtin_nontemporal_load((const f4*)x + 2 * i);       // pts 4i, 4i+1
    f4 p23 = __builtin_nontemporal_load((const f4*)x + 2 * i + 1);   // pts 4i+2, 4i+3

    f4 r;
    r.x = eval_rec(t0, p01.x, p01.y);
    r.y = eval_rec(t1, p01.z, p01.w);
    r.z = eval_rec(t2, p23.x, p23.y);
    r.w = eval_rec(t3, p23.z, p23.w);

    __builtin_nontemporal_store(r, (f4*)out + i);
}

// Fallback (round-1 style) in case ws_size can't hold the 2 MB table.
__global__ __launch_bounds__(256) void p1_eval_direct(
    const float* __restrict__ x,
    const float* __restrict__ Minv,
    const float* __restrict__ A,
    const float* __restrict__ weight,
    const int*   __restrict__ cell_ids,
    const int*   __restrict__ dofs,
    float*       __restrict__ out,
    int n_pts)
{
    int i = blockIdx.x * blockDim.x + threadIdx.x;
    if (i >= n_pts) return;
    float px = x[2 * i], py = x[2 * i + 1];
    int c = cell_ids[i];
    f2 a = ((const f2*)A)[c];
    f4 M = ((const f4*)Minv)[c];
    float dx = px - a.x, dy = py - a.y;
    float s = dx * M.x + dy * M.z;
    float t = dx * M.y + dy * M.w;
    float c0 = weight[dofs[c * 3 + 0]];
    float c1 = weight[dofs[c * 3 + 1]];
    float cc = weight[dofs[c * 3 + 2]];
    out[i] = c0 * (1.0f - s - t) + c1 * s + cc * t;
}

extern "C" void kernel_launch(void* const* d_in, const int* in_sizes, int n_in,
                              void* d_out, int out_size, void* d_ws, size_t ws_size,
                              hipStream_t stream) {
    const float* x        = (const float*)d_in[0];
    const float* Minv     = (const float*)d_in[1];
    const float* A        = (const float*)d_in[2];
    const float* weight   = (const float*)d_in[3];
    const int*   cell_ids = (const int*)d_in[4];
    const int*   dofs     = (const int*)d_in[5];
    float*       out      = (float*)d_out;

    int n_pts   = out_size;          // 4194304
    int n_cells = in_sizes[2] / 2;   // A has 2 floats/cell -> 262144
    int block = 256;

    size_t table_bytes = (size_t)n_cells * sizeof(unsigned long long);  // 2 MB

    if (ws_size >= table_bytes) {
        unsigned long long* table = (unsigned long long*)d_ws;
        int grid_pre = (n_cells + block - 1) / block;
        p1_precompute_kernel<<<grid_pre, block, 0, stream>>>(
            Minv, A, weight, dofs, table, n_cells);
        int n_quads = n_pts / 4;
        int grid_main = (n_quads + block - 1) / block;
        p1_eval_fast<<<grid_main, block, 0, stream>>>(
            x, cell_ids, table, out, n_quads);
    } else {
        int grid = (n_pts + block - 1) / block;
        p1_eval_direct<<<grid, block, 0, stream>>>(
            x, Minv, A, weight, cell_ids, dofs, out, n_pts);
    }
}